// Round 1
// baseline (834.797 us; speedup 1.0000x reference)
//
#include <hip/hip_runtime.h>
#include <float.h>

#define DIMC 512
#define WW 64
#define RR 128
#define NH 8
#define HDIM 64
#define NSEQ 65      // 1+W
#define MSEQ 129     // 1+R

typedef __attribute__((ext_vector_type(8))) short short8;
typedef __attribute__((ext_vector_type(4))) float f32x4;
typedef __attribute__((ext_vector_type(4))) unsigned int u32x4;
typedef __attribute__((ext_vector_type(4))) unsigned short u16x4;

typedef __attribute__((address_space(3))) unsigned int lds_uint;
typedef __attribute__((address_space(1))) unsigned int glob_uint;

__device__ __forceinline__ float asfloat(unsigned int u) { union { unsigned int i; float f; } v; v.i = u; return v.f; }
__device__ __forceinline__ unsigned int asuint(float f) { union { float f; unsigned int i; } v; v.f = f; return v.i; }
__device__ __forceinline__ unsigned short f2bf(float f) {
  unsigned int x = asuint(f);
  x += 0x7fffu + ((x >> 16) & 1u);   // round-to-nearest-even
  return (unsigned short)(x >> 16);
}
__device__ __forceinline__ float readlane_f(float v, int l) {
  return asfloat((unsigned int)__builtin_amdgcn_readlane((int)asuint(v), l));
}

// ---------------------------------------------------------------- converts
__global__ void convert_f32_bf16(const float* __restrict__ s,
                                 unsigned short* __restrict__ d, long n4) {
  long stride = (long)gridDim.x * blockDim.x;
  for (long i = (long)blockIdx.x * blockDim.x + threadIdx.x; i < n4; i += stride) {
    f32x4 f = ((const f32x4*)s)[i];
    u16x4 o;
    o[0] = f2bf(f[0]); o[1] = f2bf(f[1]); o[2] = f2bf(f[2]); o[3] = f2bf(f[3]);
    ((u16x4*)d)[i] = o;
  }
}

// ---------------------------------------------------------------- GEMM (NT)
// C(M,N) = A(M,K) * B(N,K)^T + bias[col];  M,N multiples of 128, K multiple of 64.
// m97 structure: 128x128 tile, BK=64, 4 waves (2x2), global_load_lds width-16.
template<int OUTBF>
__global__ __launch_bounds__(256)
void gemm_nt(const unsigned short* __restrict__ A, const unsigned short* __restrict__ Bw,
             const float* __restrict__ bias, void* __restrict__ Cout,
             long M, long N, long K) {
  __shared__ unsigned short As[128 * 64];
  __shared__ unsigned short Bs[128 * 64];
  const int tid  = threadIdx.x;
  const int lane = tid & 63;
  const int wid  = tid >> 6;
  const int wr   = wid >> 1, wc = wid & 1;
  const long mBase = (long)blockIdx.y * 128;
  const long nBase = (long)blockIdx.x * 128;
  const int r15 = lane & 15;
  const int g16 = lane >> 4;

  f32x4 acc[4][4];
#pragma unroll
  for (int a = 0; a < 4; ++a)
#pragma unroll
    for (int b = 0; b < 4; ++b) acc[a][b] = (f32x4){0.f, 0.f, 0.f, 0.f};

  const int srow = tid >> 3;        // 0..31 : row within a 32-row chunk
  const int skb  = (tid & 7) * 8;   // element offset within a row

  for (long kt = 0; kt < K; kt += 64) {
    __syncthreads();
#pragma unroll
    for (int j = 0; j < 4; ++j) {
      long row = j * 32 + srow;
      const unsigned short* ga = A  + (mBase + row) * K + kt + skb;
      const unsigned short* gb = Bw + (nBase + row) * K + kt + skb;
      __builtin_amdgcn_global_load_lds((glob_uint*)ga, (lds_uint*)(As + (j * 256 + wid * 64) * 8), 16, 0, 0);
      __builtin_amdgcn_global_load_lds((glob_uint*)gb, (lds_uint*)(Bs + (j * 256 + wid * 64) * 8), 16, 0, 0);
    }
    __syncthreads();
#pragma unroll
    for (int kk = 0; kk < 64; kk += 32) {
      short8 af[4], bfr[4];
#pragma unroll
      for (int mi = 0; mi < 4; ++mi)
        af[mi] = *(const short8*)&As[(wr * 64 + mi * 16 + r15) * 64 + kk + g16 * 8];
#pragma unroll
      for (int ni = 0; ni < 4; ++ni)
        bfr[ni] = *(const short8*)&Bs[(wc * 64 + ni * 16 + r15) * 64 + kk + g16 * 8];
#pragma unroll
      for (int mi = 0; mi < 4; ++mi)
#pragma unroll
        for (int ni = 0; ni < 4; ++ni)
          acc[mi][ni] = __builtin_amdgcn_mfma_f32_16x16x32_bf16(af[mi], bfr[ni], acc[mi][ni], 0, 0, 0);
    }
  }

  float bv[4];
  long col[4];
#pragma unroll
  for (int ni = 0; ni < 4; ++ni) { col[ni] = nBase + wc * 64 + ni * 16 + r15; bv[ni] = bias[col[ni]]; }
#pragma unroll
  for (int mi = 0; mi < 4; ++mi) {
    long row0 = mBase + wr * 64 + mi * 16 + g16 * 4;
#pragma unroll
    for (int ni = 0; ni < 4; ++ni) {
#pragma unroll
      for (int v = 0; v < 4; ++v) {
        float val = acc[mi][ni][v] + bv[ni];
        long off = (row0 + v) * N + col[ni];
        if (OUTBF) ((unsigned short*)Cout)[off] = f2bf(val);
        else       ((float*)Cout)[off] = val;
      }
    }
  }
}

// ---------------------------------------------------------------- attention
// One block per (b_, h). 4 waves. Lanes own score columns {lane, lane+64};
// column 128 computed uniformly by every lane. fp32 compute.
__global__ __launch_bounds__(256)
void attn_fused(const unsigned short* __restrict__ qb,
                const unsigned short* __restrict__ kvb,
                unsigned short* __restrict__ aob,
                const float* __restrict__ rel_table,
                const float* __restrict__ cls_self,
                const float* __restrict__ cls_up,
                const float* __restrict__ cls_down,
                const int* __restrict__ mask_left,
                const int* __restrict__ mask_right,
                const int* __restrict__ nWp, int mcL) {
  __shared__ float ks[MSEQ][68];
  __shared__ float qs[NSEQ][68];
  const int h   = blockIdx.x;
  const int b_  = blockIdx.y;
  const int tid = threadIdx.x, lane = tid & 63, wid = tid >> 6;

  const int nW = nWp[0];
  const int w  = b_ % nW;
  const int mc = min(mcL, nW);
  const bool useL = (w < mc);
  const bool useR = (w >= nW - mc);
  const int wR = mcL - mc + (w - (nW - mc));

  const unsigned short* qg = qb  + ((long)b_ * NSEQ) * DIMC + h * HDIM;
  const unsigned short* kg = kvb + ((long)b_ * MSEQ) * (2 * DIMC) + h * HDIM;
  const unsigned short* vg = kg + DIMC;

  // ---- stage K (bf16 -> fp32 LDS)
  for (int idx = tid; idx < MSEQ * 8; idx += 256) {
    int r = idx >> 3, s8 = (idx & 7) * 8;
    u32x4 u = *(const u32x4*)(kg + (long)r * (2 * DIMC) + s8);
    f32x4 fa, fb;
    fa[0] = asfloat(u[0] << 16); fa[1] = asfloat(u[0] & 0xffff0000u);
    fa[2] = asfloat(u[1] << 16); fa[3] = asfloat(u[1] & 0xffff0000u);
    fb[0] = asfloat(u[2] << 16); fb[1] = asfloat(u[2] & 0xffff0000u);
    fb[2] = asfloat(u[3] << 16); fb[3] = asfloat(u[3] & 0xffff0000u);
    *(f32x4*)&ks[r][s8] = fa; *(f32x4*)&ks[r][s8 + 4] = fb;
  }
  // ---- stage Q
  for (int idx = tid; idx < NSEQ * 8; idx += 256) {
    int r = idx >> 3, s8 = (idx & 7) * 8;
    u32x4 u = *(const u32x4*)(qg + (long)r * DIMC + s8);
    f32x4 fa, fb;
    fa[0] = asfloat(u[0] << 16); fa[1] = asfloat(u[0] & 0xffff0000u);
    fa[2] = asfloat(u[1] << 16); fa[3] = asfloat(u[1] & 0xffff0000u);
    fb[0] = asfloat(u[2] << 16); fb[1] = asfloat(u[2] & 0xffff0000u);
    fb[2] = asfloat(u[3] << 16); fb[3] = asfloat(u[3] & 0xffff0000u);
    *(f32x4*)&qs[r][s8] = fa; *(f32x4*)&qs[r][s8 + 4] = fb;
  }
  __syncthreads();

  float s0[17], s1[17], s2[17];
#pragma unroll
  for (int r = 0; r < 17; ++r) { s0[r] = 0.f; s1[r] = 0.f; s2[r] = 0.f; }

  // ---- scores: d-group outer, rows inner; k cached in registers
  for (int dg = 0; dg < 8; ++dg) {
    const int d0 = dg * 8;
    f32x4 k0a = *(const f32x4*)&ks[lane][d0],      k0b = *(const f32x4*)&ks[lane][d0 + 4];
    f32x4 k1a = *(const f32x4*)&ks[lane + 64][d0], k1b = *(const f32x4*)&ks[lane + 64][d0 + 4];
    f32x4 k2a = *(const f32x4*)&ks[128][d0],       k2b = *(const f32x4*)&ks[128][d0 + 4];
#pragma unroll
    for (int r = 0; r < 17; ++r) {
      int i = wid + 4 * r;
      if (i < NSEQ) {
        f32x4 qa = *(const f32x4*)&qs[i][d0], qb4 = *(const f32x4*)&qs[i][d0 + 4];
        s0[r] += qa[0]*k0a[0] + qa[1]*k0a[1] + qa[2]*k0a[2] + qa[3]*k0a[3]
               + qb4[0]*k0b[0] + qb4[1]*k0b[1] + qb4[2]*k0b[2] + qb4[3]*k0b[3];
        s1[r] += qa[0]*k1a[0] + qa[1]*k1a[1] + qa[2]*k1a[2] + qa[3]*k1a[3]
               + qb4[0]*k1b[0] + qb4[1]*k1b[1] + qb4[2]*k1b[2] + qb4[3]*k1b[3];
        s2[r] += qa[0]*k2a[0] + qa[1]*k2a[1] + qa[2]*k2a[2] + qa[3]*k2a[3]
               + qb4[0]*k2b[0] + qb4[1]*k2b[1] + qb4[2]*k2b[2] + qb4[3]*k2b[3];
      }
    }
  }

  // ---- scale + bias + mask + softmax (per row)
  const int c0 = lane, c1 = lane + 64;
#pragma unroll
  for (int r = 0; r < 17; ++r) {
    int i = wid + 4 * r;
    if (i < NSEQ) {
      float b0, b1, b2;
      if (i == 0) {
        b0 = (c0 == 0) ? cls_self[h] : cls_up[h * RR + (c0 > 0 ? c0 - 1 : 0)];
        b1 = cls_up[h * RR + c1 - 1];
        b2 = cls_up[h * RR + 127];
      } else {
        int rid0 = i - c0 + 127; if (rid0 > 190) rid0 = 190;
        b0 = (c0 == 0) ? cls_down[h * WW + i - 1] : rel_table[rid0 * NH + h];
        b1 = rel_table[(i - c1 + 127) * NH + h];
        b2 = rel_table[(i - 1) * NH + h];
      }
      float v0 = s0[r] * 0.125f + b0;
      float v1 = s1[r] * 0.125f + b1;
      float v2 = s2[r] * 0.125f + b2;
      if (useL) {
        const int* ml = mask_left + ((long)w * NSEQ + i) * MSEQ;
        if (ml[c0])  v0 = -FLT_MAX;
        if (ml[c1])  v1 = -FLT_MAX;
        if (ml[128]) v2 = -FLT_MAX;
      }
      if (useR) {
        const int* mr = mask_right + ((long)wR * NSEQ + i) * MSEQ;
        if (mr[c0])  v0 = -FLT_MAX;
        if (mr[c1])  v1 = -FLT_MAX;
        if (mr[128]) v2 = -FLT_MAX;
      }
      float m = fmaxf(v0, v1);
#pragma unroll
      for (int off = 32; off >= 1; off >>= 1) m = fmaxf(m, __shfl_xor(m, off, 64));
      m = fmaxf(m, v2);  // col 128 (uniform)
      float p0 = __expf(v0 - m), p1 = __expf(v1 - m), p2 = __expf(v2 - m);
      float t = p0 + p1;
#pragma unroll
      for (int off = 32; off >= 1; off >>= 1) t += __shfl_xor(t, off, 64);
      t += p2;
      float inv = 1.0f / t;
      s0[r] = p0 * inv; s1[r] = p1 * inv; s2[r] = p2 * inv;
    }
  }

  __syncthreads();   // all waves done reading K from LDS
  // ---- stage V into ks
  for (int idx = tid; idx < MSEQ * 8; idx += 256) {
    int r = idx >> 3, s8 = (idx & 7) * 8;
    u32x4 u = *(const u32x4*)(vg + (long)r * (2 * DIMC) + s8);
    f32x4 fa, fb;
    fa[0] = asfloat(u[0] << 16); fa[1] = asfloat(u[0] & 0xffff0000u);
    fa[2] = asfloat(u[1] << 16); fa[3] = asfloat(u[1] & 0xffff0000u);
    fb[0] = asfloat(u[2] << 16); fb[1] = asfloat(u[2] & 0xffff0000u);
    fb[2] = asfloat(u[3] << 16); fb[3] = asfloat(u[3] & 0xffff0000u);
    *(f32x4*)&ks[r][s8] = fa; *(f32x4*)&ks[r][s8 + 4] = fb;
  }
  __syncthreads();

  // ---- PV: lane owns output dim d = lane; broadcast p via v_readlane (VALU pipe)
  float oa[17];
#pragma unroll
  for (int r = 0; r < 17; ++r) oa[r] = 0.f;

  for (int c = 0; c < 64; ++c) {
    float vc = ks[c][lane];
#pragma unroll
    for (int r = 0; r < 17; ++r) oa[r] += readlane_f(s0[r], c) * vc;
  }
  for (int c = 0; c < 64; ++c) {
    float vc = ks[c + 64][lane];
#pragma unroll
    for (int r = 0; r < 17; ++r) oa[r] += readlane_f(s1[r], c) * vc;
  }
  {
    float vc = ks[128][lane];
#pragma unroll
    for (int r = 0; r < 17; ++r) oa[r] += s2[r] * vc;
  }

#pragma unroll
  for (int r = 0; r < 17; ++r) {
    int i = wid + 4 * r;
    if (i < NSEQ)
      aob[((long)b_ * NSEQ + i) * DIMC + h * HDIM + lane] = f2bf(oa[r]);
  }
}

// ---------------------------------------------------------------- launch
extern "C" void kernel_launch(void* const* d_in, const int* in_sizes, int n_in,
                              void* d_out, int out_size, void* d_ws, size_t ws_size,
                              hipStream_t stream) {
  const float* x          = (const float*)d_in[0];
  const float* x_         = (const float*)d_in[1];
  const int*   mask_left  = (const int*)d_in[2];
  const int*   mask_right = (const int*)d_in[3];
  const int*   nWp        = (const int*)d_in[4];
  const float* rel_table  = (const float*)d_in[5];
  const float* cls_self   = (const float*)d_in[6];
  const float* cls_up     = (const float*)d_in[7];
  const float* cls_down   = (const float*)d_in[8];
  const float* Wq         = (const float*)d_in[9];
  const float* bq         = (const float*)d_in[10];
  const float* Wkv        = (const float*)d_in[11];
  const float* bkv        = (const float*)d_in[12];
  const float* Wp         = (const float*)d_in[13];
  const float* bp         = (const float*)d_in[14];

  const long B_  = in_sizes[0] / (NSEQ * DIMC);          // 512
  const int  mcL = in_sizes[2] / (NSEQ * MSEQ);          // 4
  const long Mq  = B_ * NSEQ;                            // 33280
  const long Mkv = B_ * MSEQ;                            // 66048

  // workspace layout (bf16 elements)
  unsigned short* xb    = (unsigned short*)d_ws;
  unsigned short* x_b   = xb    + Mq  * DIMC;
  unsigned short* wqb   = x_b   + Mkv * DIMC;
  unsigned short* wkvb  = wqb   + DIMC * DIMC;
  unsigned short* wpb   = wkvb  + 2 * DIMC * DIMC;
  unsigned short* qbuf  = wpb   + DIMC * DIMC;
  unsigned short* kvbuf = qbuf  + Mq  * DIMC;
  unsigned short* aob   = kvbuf + Mkv * 2 * DIMC;
  const size_t needed = (size_t)(Mq * DIMC * 3 + Mkv * DIMC * 3 + 4 * DIMC * DIMC) * 2;
  if (ws_size < needed) return;  // workspace too small: bail (bench will fail loudly)

  auto cv = [&](const float* s, unsigned short* d, long n) {
    long n4 = n / 4;
    int blocks = (int)((n4 + 255) / 256); if (blocks > 8192) blocks = 8192;
    convert_f32_bf16<<<blocks, 256, 0, stream>>>(s, d, n4);
  };
  cv(x,   xb,   Mq * DIMC);
  cv(x_,  x_b,  Mkv * DIMC);
  cv(Wq,  wqb,  (long)DIMC * DIMC);
  cv(Wkv, wkvb, 2L * DIMC * DIMC);
  cv(Wp,  wpb,  (long)DIMC * DIMC);

  gemm_nt<1><<<dim3(DIMC / 128, (unsigned)(Mq / 128)), 256, 0, stream>>>(
      xb, wqb, bq, qbuf, Mq, DIMC, DIMC);
  gemm_nt<1><<<dim3(2 * DIMC / 128, (unsigned)(Mkv / 128)), 256, 0, stream>>>(
      x_b, wkvb, bkv, kvbuf, Mkv, 2 * DIMC, DIMC);

  attn_fused<<<dim3(NH, (unsigned)B_), 256, 0, stream>>>(
      qbuf, kvbuf, aob, rel_table, cls_self, cls_up, cls_down,
      mask_left, mask_right, nWp, mcL);

  gemm_nt<0><<<dim3(DIMC / 128, (unsigned)(Mq / 128)), 256, 0, stream>>>(
      aob, wpb, bp, d_out, Mq, DIMC, DIMC);
}

// Round 3
// 640.763 us; speedup vs baseline: 1.3028x; 1.3028x over previous
//
#include <hip/hip_runtime.h>
#include <float.h>

#define DIMC 512
#define WW 64
#define RR 128
#define NH 8
#define HDIM 64
#define NSEQ 65      // 1+W
#define MSEQ 129     // 1+R

typedef __attribute__((ext_vector_type(8))) short short8;
typedef __attribute__((ext_vector_type(4))) float f32x4;
typedef __attribute__((ext_vector_type(4))) unsigned int u32x4;
typedef __attribute__((ext_vector_type(4))) unsigned short u16x4;

typedef __attribute__((address_space(3))) unsigned int lds_uint;
typedef __attribute__((address_space(1))) unsigned int glob_uint;

__device__ __forceinline__ float asfloat(unsigned int u) { union { unsigned int i; float f; } v; v.i = u; return v.f; }
__device__ __forceinline__ unsigned int asuint(float f) { union { float f; unsigned int i; } v; v.f = f; return v.i; }
__device__ __forceinline__ unsigned short f2bf(float f) {
  unsigned int x = asuint(f);
  x += 0x7fffu + ((x >> 16) & 1u);   // round-to-nearest-even
  return (unsigned short)(x >> 16);
}
__device__ __forceinline__ float bf2f(unsigned short b) { return asfloat(((unsigned int)b) << 16); }

__device__ __forceinline__ short8 ld_b64x2(const unsigned short* p) {
  typedef __attribute__((ext_vector_type(4))) short sh4;
  sh4 lo = *(const sh4*)p;
  sh4 hi = *(const sh4*)(p + 4);
  short8 r;
  r[0] = lo[0]; r[1] = lo[1]; r[2] = lo[2]; r[3] = lo[3];
  r[4] = hi[0]; r[5] = hi[1]; r[6] = hi[2]; r[7] = hi[3];
  return r;
}

// ---------------------------------------------------------------- converts
__global__ void convert_f32_bf16(const float* __restrict__ s,
                                 unsigned short* __restrict__ d, long n4) {
  long stride = (long)gridDim.x * blockDim.x;
  for (long i = (long)blockIdx.x * blockDim.x + threadIdx.x; i < n4; i += stride) {
    f32x4 f = ((const f32x4*)s)[i];
    u16x4 o;
    o[0] = f2bf(f[0]); o[1] = f2bf(f[1]); o[2] = f2bf(f[2]); o[3] = f2bf(f[3]);
    ((u16x4*)d)[i] = o;
  }
}

// ---------------------------------------------------------------- GEMM (NT)
// C(M,N) = A(M,K) * B(N,K)^T + bias[col];  M,N multiples of 128, K multiple of 64.
template<int OUTBF>
__global__ __launch_bounds__(256)
void gemm_nt(const unsigned short* __restrict__ A, const unsigned short* __restrict__ Bw,
             const float* __restrict__ bias, void* __restrict__ Cout,
             long M, long N, long K) {
  __shared__ unsigned short As[128 * 64];
  __shared__ unsigned short Bs[128 * 64];
  const int tid  = threadIdx.x;
  const int lane = tid & 63;
  const int wid  = tid >> 6;
  const int wr   = wid >> 1, wc = wid & 1;
  const long mBase = (long)blockIdx.y * 128;
  const long nBase = (long)blockIdx.x * 128;
  const int r15 = lane & 15;
  const int g16 = lane >> 4;

  f32x4 acc[4][4];
#pragma unroll
  for (int a = 0; a < 4; ++a)
#pragma unroll
    for (int b = 0; b < 4; ++b) acc[a][b] = (f32x4){0.f, 0.f, 0.f, 0.f};

  const int srow = tid >> 3;        // 0..31 : row within a 32-row chunk
  const int skb  = (tid & 7) * 8;   // element offset within a row

  for (long kt = 0; kt < K; kt += 64) {
    __syncthreads();
#pragma unroll
    for (int j = 0; j < 4; ++j) {
      long row = j * 32 + srow;
      const unsigned short* ga = A  + (mBase + row) * K + kt + skb;
      const unsigned short* gb = Bw + (nBase + row) * K + kt + skb;
      __builtin_amdgcn_global_load_lds((glob_uint*)ga, (lds_uint*)(As + (j * 256 + wid * 64) * 8), 16, 0, 0);
      __builtin_amdgcn_global_load_lds((glob_uint*)gb, (lds_uint*)(Bs + (j * 256 + wid * 64) * 8), 16, 0, 0);
    }
    __syncthreads();
#pragma unroll
    for (int kk = 0; kk < 64; kk += 32) {
      short8 af[4], bfr[4];
#pragma unroll
      for (int mi = 0; mi < 4; ++mi)
        af[mi] = *(const short8*)&As[(wr * 64 + mi * 16 + r15) * 64 + kk + g16 * 8];
#pragma unroll
      for (int ni = 0; ni < 4; ++ni)
        bfr[ni] = *(const short8*)&Bs[(wc * 64 + ni * 16 + r15) * 64 + kk + g16 * 8];
#pragma unroll
      for (int mi = 0; mi < 4; ++mi)
#pragma unroll
        for (int ni = 0; ni < 4; ++ni)
          acc[mi][ni] = __builtin_amdgcn_mfma_f32_16x16x32_bf16(af[mi], bfr[ni], acc[mi][ni], 0, 0, 0);
    }
  }

  float bv[4];
  long col[4];
#pragma unroll
  for (int ni = 0; ni < 4; ++ni) { col[ni] = nBase + wc * 64 + ni * 16 + r15; bv[ni] = bias[col[ni]]; }
#pragma unroll
  for (int mi = 0; mi < 4; ++mi) {
    long row0 = mBase + wr * 64 + mi * 16 + g16 * 4;
#pragma unroll
    for (int ni = 0; ni < 4; ++ni) {
#pragma unroll
      for (int v = 0; v < 4; ++v) {
        float val = acc[mi][ni][v] + bv[ni];
        long off = (row0 + v) * N + col[ni];
        if (OUTBF) ((unsigned short*)Cout)[off] = f2bf(val);
        else       ((float*)Cout)[off] = val;
      }
    }
  }
}

// ---------------------------------------------------------------- MFMA attention
// One block per (b_, h). 4 waves. Wave w owns M-tile w (rows 16w..16w+15);
// wave 0 also owns M-tile 4 (rows 64..79, only row 64 valid).
// LDS layout (u16 elems):
//   [VT_OFF]  Vt[64][VT_STR=140]   : V^T, cols 0..128 valid       (8960)
//   [K_OFF]   K [144][64]          : rows 0..128 valid, swizzled  (9216)
//   [Q_OFF]   Q [80][64]           : rows 65..79 dup row 64, swz  (5120)
//   [P_OFF=K_OFF] P[80][P_STR=136] : overlays K+Q after QK^T      (10880)
#define VT_OFF 0
#define VT_STR 140
#define K_OFF  (64 * VT_STR)          // 8960
#define Q_OFF  (K_OFF + 144 * 64)     // 18176
#define P_OFF  K_OFF
#define P_STR  136
#define SMEM_ELEMS (Q_OFF + 80 * 64)  // 23296 elems = 46592 B -> 3 blocks/CU

__global__ __launch_bounds__(256, 3)
void attn_mfma(const unsigned short* __restrict__ qb,
               const unsigned short* __restrict__ kvb,
               unsigned short* __restrict__ aob,
               const float* __restrict__ rel_table,
               const float* __restrict__ cls_self,
               const float* __restrict__ cls_up,
               const float* __restrict__ cls_down,
               const int* __restrict__ mask_left,
               const int* __restrict__ mask_right,
               const int* __restrict__ nWp, int mcL) {
  __shared__ unsigned short smem[SMEM_ELEMS];
  const int h   = blockIdx.x;
  const int b_  = blockIdx.y;
  const int tid = threadIdx.x, lane = tid & 63, wid = tid >> 6;
  const int r15 = lane & 15, g16 = lane >> 4;

  const int nW = nWp[0];
  const int w  = b_ % nW;
  const int mc = min(mcL, nW);
  const bool useL = (w < mc);
  const bool useR = (w >= nW - mc);
  const int wR = mcL - mc + (w - (nW - mc));

  const unsigned short* kgbase = kvb + (long)b_ * MSEQ * (2 * DIMC) + h * HDIM;       // K, row stride 1024
  const unsigned short* vgbase = kgbase + DIMC;                                       // V
  const unsigned short* qgbase = qb  + (long)b_ * NSEQ * DIMC + h * HDIM;             // Q, row stride 512

  // ---- staging. Source col pre-swizzled (rule #21) so fragment reads can
  // XOR-unswizzle: LDS[row][col16 ^ (row&7)] = global[row][col16].
  const int lr  = lane >> 3;                                  // row within 8-row chunk
  const int lcs = ((lane & 7) ^ (lr & 7)) * 8;                // swizzled source col (elems)
  // K rows 0..128 (+dup pad)
#pragma unroll
  for (int j = 0; j < 4; ++j) {
    int chunk = j * 4 + wid;                                  // 0..15 -> rows 0..127
    int gr = chunk * 8 + lr;
    __builtin_amdgcn_global_load_lds((glob_uint*)(kgbase + (long)gr * (2 * DIMC) + lcs),
                                     (lds_uint*)(smem + K_OFF + chunk * 512), 16, 0, 0);
  }
  if (wid == 0) {                                             // chunk 16: rows 128..135 (clamp->dup 128)
    __builtin_amdgcn_global_load_lds((glob_uint*)(kgbase + (long)128 * (2 * DIMC) + lcs),
                                     (lds_uint*)(smem + K_OFF + 16 * 512), 16, 0, 0);
  }
  // Q rows 0..79 (clamp >64 -> dup row 64)
#pragma unroll
  for (int j = 0; j < 2; ++j) {
    int chunk = j * 4 + wid;                                  // 0..7 -> rows 0..63
    int gr = chunk * 8 + lr;
    __builtin_amdgcn_global_load_lds((glob_uint*)(qgbase + (long)gr * DIMC + lcs),
                                     (lds_uint*)(smem + Q_OFF + chunk * 512), 16, 0, 0);
  }
  if (wid < 2) {                                              // chunks 8,9: rows 64..79
    int chunk = 8 + wid;
    int gr = min(chunk * 8 + lr, NSEQ - 1);
    __builtin_amdgcn_global_load_lds((glob_uint*)(qgbase + (long)gr * DIMC + lcs),
                                     (lds_uint*)(smem + Q_OFF + chunk * 512), 16, 0, 0);
  }
  // V transpose: Vt[d][c] = V[c][d], cols 0..128
  for (int it = 0; it < 5; ++it) {
    int idx = it * 256 + tid;
    if (idx < MSEQ * 8) {
      int c = idx >> 3, d0 = (idx & 7) * 8;
      u32x4 u = *(const u32x4*)(vgbase + (long)c * (2 * DIMC) + d0);
#pragma unroll
      for (int jj = 0; jj < 4; ++jj) {
        smem[VT_OFF + (d0 + 2 * jj) * VT_STR + c]     = (unsigned short)(u[jj] & 0xffffu);
        smem[VT_OFF + (d0 + 2 * jj + 1) * VT_STR + c] = (unsigned short)(u[jj] >> 16);
      }
    }
  }
  __syncthreads();

  // ---- phase A: QK^T, S in registers. S[t][ni][v]: row=i0+g16*4+v, col=16ni+r15.
  f32x4 S[2][9];
  const int swz = (r15 & 7) << 3;
#pragma unroll
  for (int t = 0; t < 2; ++t) {
    if (t == 1 && wid != 0) continue;
    const int i0 = (t == 0 ? wid : 4) * 16;
    short8 a0 = *(const short8*)&smem[Q_OFF + (i0 + r15) * 64 + ((g16 * 8) ^ swz)];
    short8 a1 = *(const short8*)&smem[Q_OFF + (i0 + r15) * 64 + ((32 + g16 * 8) ^ swz)];
#pragma unroll
    for (int ni = 0; ni < 9; ++ni) {
      short8 b0 = *(const short8*)&smem[K_OFF + (ni * 16 + r15) * 64 + ((g16 * 8) ^ swz)];
      short8 b1 = *(const short8*)&smem[K_OFF + (ni * 16 + r15) * 64 + ((32 + g16 * 8) ^ swz)];
      f32x4 c = (f32x4){0.f, 0.f, 0.f, 0.f};
      c = __builtin_amdgcn_mfma_f32_16x16x32_bf16(a0, b0, c, 0, 0, 0);
      c = __builtin_amdgcn_mfma_f32_16x16x32_bf16(a1, b1, c, 0, 0, 0);
      S[t][ni] = c;
    }
  }
  __syncthreads();   // all K/Q reads done before P overwrites that region

  // ---- phase B: scale+bias+mask+softmax in registers; write P (bf16) to LDS.
  float p128[2][4];
#pragma unroll
  for (int t = 0; t < 2; ++t) {
    if (t == 1 && wid != 0) continue;
    const int i0 = (t == 0 ? wid : 4) * 16;
#pragma unroll
    for (int v = 0; v < 4; ++v) {
      int row  = i0 + g16 * 4 + v;
      int rowb = min(row, NSEQ - 1);
#pragma unroll
      for (int ni = 0; ni < 9; ++ni) {
        int col = ni * 16 + r15;
        float val;
        if (col > 128) {
          val = -FLT_MAX;
        } else {
          float bias;
          if (row == 0) bias = (col == 0) ? cls_self[h] : cls_up[h * RR + col - 1];
          else bias = (col == 0) ? cls_down[h * WW + rowb - 1]
                                 : rel_table[min(rowb - col + 127, 190) * NH + h];
          val = S[t][ni][v] * 0.125f + bias;
          if (useL && mask_left[((long)w * NSEQ + rowb) * MSEQ + col])  val = -FLT_MAX;
          if (useR && mask_right[((long)wR * NSEQ + rowb) * MSEQ + col]) val = -FLT_MAX;
        }
        S[t][ni][v] = val;
      }
    }
#pragma unroll
    for (int v = 0; v < 4; ++v) {
      float m = S[t][0][v];
#pragma unroll
      for (int ni = 1; ni < 9; ++ni) m = fmaxf(m, S[t][ni][v]);
#pragma unroll
      for (int off = 1; off < 16; off <<= 1) m = fmaxf(m, __shfl_xor(m, off, 64));
      float sum = 0.f;
#pragma unroll
      for (int ni = 0; ni < 9; ++ni) {
        float p = __expf(S[t][ni][v] - m);
        S[t][ni][v] = p;
        sum += p;
      }
#pragma unroll
      for (int off = 1; off < 16; off <<= 1) sum += __shfl_xor(sum, off, 64);
      float inv = 1.0f / sum;
#pragma unroll
      for (int ni = 0; ni < 9; ++ni) S[t][ni][v] *= inv;
    }
#pragma unroll
    for (int ni = 0; ni < 8; ++ni)
#pragma unroll
      for (int v = 0; v < 4; ++v)
        smem[P_OFF + (i0 + g16 * 4 + v) * P_STR + ni * 16 + r15] = f2bf(S[t][ni][v]);
#pragma unroll
    for (int v = 0; v < 4; ++v) p128[t][v] = S[t][8][v];   // valid in lanes r15==0
  }
  __syncthreads();

  // ---- phase C: PV MFMAs (k = 0..127) + rank-1 col-128 + store.
#pragma unroll
  for (int t = 0; t < 2; ++t) {
    if (t == 1 && wid != 0) continue;
    const int i0 = (t == 0 ? wid : 4) * 16;
    short8 pa[4];
#pragma unroll
    for (int kk = 0; kk < 4; ++kk)
      pa[kk] = *(const short8*)&smem[P_OFF + (i0 + r15) * P_STR + kk * 32 + g16 * 8];
    f32x4 acc[4];
#pragma unroll
    for (int nt = 0; nt < 4; ++nt) acc[nt] = (f32x4){0.f, 0.f, 0.f, 0.f};
#pragma unroll
    for (int nt = 0; nt < 4; ++nt)
#pragma unroll
      for (int kk = 0; kk < 4; ++kk) {
        short8 bv = ld_b64x2(&smem[VT_OFF + (nt * 16 + r15) * VT_STR + kk * 32 + g16 * 8]);
        acc[nt] = __builtin_amdgcn_mfma_f32_16x16x32_bf16(pa[kk], bv, acc[nt], 0, 0, 0);
      }
    float p1b[4];
#pragma unroll
    for (int v = 0; v < 4; ++v) p1b[v] = __shfl(p128[t][v], (lane & 48), 64);
#pragma unroll
    for (int nt = 0; nt < 4; ++nt) {
      float v128 = bf2f(smem[VT_OFF + (nt * 16 + r15) * VT_STR + 128]);
#pragma unroll
      for (int v = 0; v < 4; ++v) {
        int row = i0 + g16 * 4 + v;
        if (row < NSEQ) {
          float o = acc[nt][v] + p1b[v] * v128;
          aob[((long)b_ * NSEQ + row) * DIMC + h * HDIM + nt * 16 + r15] = f2bf(o);
        }
      }
    }
  }
}

// ---------------------------------------------------------------- launch
extern "C" void kernel_launch(void* const* d_in, const int* in_sizes, int n_in,
                              void* d_out, int out_size, void* d_ws, size_t ws_size,
                              hipStream_t stream) {
  const float* x          = (const float*)d_in[0];
  const float* x_         = (const float*)d_in[1];
  const int*   mask_left  = (const int*)d_in[2];
  const int*   mask_right = (const int*)d_in[3];
  const int*   nWp        = (const int*)d_in[4];
  const float* rel_table  = (const float*)d_in[5];
  const float* cls_self   = (const float*)d_in[6];
  const float* cls_up     = (const float*)d_in[7];
  const float* cls_down   = (const float*)d_in[8];
  const float* Wq         = (const float*)d_in[9];
  const float* bq         = (const float*)d_in[10];
  const float* Wkv        = (const float*)d_in[11];
  const float* bkv        = (const float*)d_in[12];
  const float* Wp         = (const float*)d_in[13];
  const float* bp         = (const float*)d_in[14];

  const long B_  = in_sizes[0] / (NSEQ * DIMC);          // 512
  const int  mcL = in_sizes[2] / (NSEQ * MSEQ);          // 4
  const long Mq  = B_ * NSEQ;                            // 33280
  const long Mkv = B_ * MSEQ;                            // 66048

  // workspace layout (bf16 elements)
  unsigned short* xb    = (unsigned short*)d_ws;
  unsigned short* x_b   = xb    + Mq  * DIMC;
  unsigned short* wqb   = x_b   + Mkv * DIMC;
  unsigned short* wkvb  = wqb   + DIMC * DIMC;
  unsigned short* wpb   = wkvb  + 2 * DIMC * DIMC;
  unsigned short* qbuf  = wpb   + DIMC * DIMC;
  unsigned short* kvbuf = qbuf  + Mq  * DIMC;
  unsigned short* aob   = kvbuf + Mkv * 2 * DIMC;
  const size_t needed = (size_t)(Mq * DIMC * 3 + Mkv * DIMC * 3 + 4 * DIMC * DIMC) * 2;
  if (ws_size < needed) return;

  auto cv = [&](const float* s, unsigned short* d, long n) {
    long n4 = n / 4;
    int blocks = (int)((n4 + 255) / 256); if (blocks > 8192) blocks = 8192;
    convert_f32_bf16<<<blocks, 256, 0, stream>>>(s, d, n4);
  };
  cv(x,   xb,   Mq * DIMC);
  cv(x_,  x_b,  Mkv * DIMC);
  cv(Wq,  wqb,  (long)DIMC * DIMC);
  cv(Wkv, wkvb, 2L * DIMC * DIMC);
  cv(Wp,  wpb,  (long)DIMC * DIMC);

  gemm_nt<1><<<dim3(DIMC / 128, (unsigned)(Mq / 128)), 256, 0, stream>>>(
      xb, wqb, bq, qbuf, Mq, DIMC, DIMC);
  gemm_nt<1><<<dim3(2 * DIMC / 128, (unsigned)(Mkv / 128)), 256, 0, stream>>>(
      x_b, wkvb, bkv, kvbuf, Mkv, 2 * DIMC, DIMC);

  attn_mfma<<<dim3(NH, (unsigned)B_), 256, 0, stream>>>(
      qbuf, kvbuf, aob, rel_table, cls_self, cls_up, cls_down,
      mask_left, mask_right, nWp, mcL);

  gemm_nt<0><<<dim3(DIMC / 128, (unsigned)(Mq / 128)), 256, 0, stream>>>(
      aob, wpb, bp, d_out, Mq, DIMC, DIMC);
}